// Round 4
// baseline (261.775 us; speedup 1.0000x reference)
//
#include <hip/hip_runtime.h>

// SSIM loss, fp32, x/y: (32,3,512,512), scalar mean output.
// R4: no cross-lane ops in the hot loop.
//   - Lane L owns output cols [8L..8L+7]; per (row, input) it loads 2 aligned
//     float4 (cols 8L..8L+7) + 2 scalar dwords (cols reflect(8L-1),
//     reflect(8L+8)). The scalars hit the same 64B lines as the float4s ->
//     L1 hits. No shuffles, no predication, no divergence in the body.
//   - Stateless per-output-row iterations (3 window rows loaded fresh; rows
//     r-1, r come from L1/L2). 24 independent VMEM per row, unroll 2 -> ~48
//     loads in flight per wave.
//   - Grid 3072 blocks (12/CU) for TLP.
//   - Block partials -> d_ws, 1-block reduce writes the mean.

#define IMG_H 512
#define IMG_W 512
#define N_PLANES 96                    // 32 * 3
#define RPW 4                          // rows per wave
#define WAVES_PER_BLOCK 4
#define ROWS_PER_BLOCK (RPW * WAVES_PER_BLOCK)            // 16
#define BLOCKS_PER_PLANE (IMG_H / ROWS_PER_BLOCK)         // 32
#define N_MAIN_BLOCKS (N_PLANES * BLOCKS_PER_PLANE)       // 3072
#define TOTAL_ELEMS 25165824.0f        // 32*3*512*512

__device__ __forceinline__ int reflect512(int i) {
    i = i < 0 ? -i : i;
    return i > (IMG_H - 1) ? (2 * (IMG_H - 1) - i) : i;
}

// 10 columns for one (row, input): [8L-1, 8L..8L+7, 8L+8]
struct R10 { float v[10]; };

__device__ __forceinline__ R10 load10(const float* __restrict__ row,
                                      int vidx, int cl, int cr) {
    R10 o;
    const float4 a = ((const float4*)row)[vidx];
    const float4 b = ((const float4*)row)[vidx + 1];
    o.v[0] = row[cl];
    o.v[1] = a.x; o.v[2] = a.y; o.v[3] = a.z; o.v[4] = a.w;
    o.v[5] = b.x; o.v[6] = b.y; o.v[7] = b.z; o.v[8] = b.w;
    o.v[9] = row[cr];
    return o;
}

__global__ __launch_bounds__(256, 4)
void ssim_main_kernel(const float* __restrict__ x, const float* __restrict__ y,
                      float* __restrict__ partials) {
    const int blk   = blockIdx.x;
    const int plane = blk / BLOCKS_PER_PLANE;
    const int rblk  = blk % BLOCKS_PER_PLANE;
    const int wave  = threadIdx.x >> 6;
    const int lane  = threadIdx.x & 63;

    const int r0   = (rblk * WAVES_PER_BLOCK + wave) * RPW;
    const int vidx = lane * 2;                        // float4 index in row
    const int c0   = lane * 8;
    const int cl   = reflect512(c0 - 1);              // lane 0: -1 -> 1
    const int cr   = reflect512(c0 + 8);              // lane 63: 512 -> 510

    const float* px = x + (size_t)plane * (IMG_H * IMG_W);
    const float* py = y + (size_t)plane * (IMG_H * IMG_W);

    const float C1v  = 0.0001f;   // 0.01^2
    const float C2v  = 0.0009f;   // 0.03^2
    const float inv9 = 1.0f / 9.0f;

    float acc = 0.0f;

    #pragma unroll 2
    for (int i = 0; i < RPW; ++i) {
        const int r  = r0 + i;
        const int rm = reflect512(r - 1);
        const int rp = reflect512(r + 1);

        const float* xrm = px + (size_t)rm * IMG_W;
        const float* xr0 = px + (size_t)r  * IMG_W;
        const float* xrp = px + (size_t)rp * IMG_W;
        const float* yrm = py + (size_t)rm * IMG_W;
        const float* yr0 = py + (size_t)r  * IMG_W;
        const float* yrp = py + (size_t)rp * IMG_W;

        const R10 xa = load10(xrm, vidx, cl, cr);
        const R10 xb = load10(xr0, vidx, cl, cr);
        const R10 xc = load10(xrp, vidx, cl, cr);
        const R10 ya = load10(yrm, vidx, cl, cr);
        const R10 yb = load10(yr0, vidx, cl, cr);
        const R10 yc = load10(yrp, vidx, cl, cr);

        // vertical 3-row sums per column (10 cols)
        float VSx[10], VSy[10], VSxx[10], VSyy[10], VSxy[10];
        #pragma unroll
        for (int c = 0; c < 10; ++c) {
            const float x1 = xa.v[c], x2 = xb.v[c], x3 = xc.v[c];
            const float y1 = ya.v[c], y2 = yb.v[c], y3 = yc.v[c];
            VSx[c]  = x1 + x2 + x3;
            VSy[c]  = y1 + y2 + y3;
            VSxx[c] = fmaf(x1, x1, fmaf(x2, x2, x3 * x3));
            VSyy[c] = fmaf(y1, y1, fmaf(y2, y2, y3 * y3));
            VSxy[c] = fmaf(x1, y1, fmaf(x2, y2, x3 * y3));
        }

        // horizontal 3-tap + SSIM per output column j (cols 8L+j)
        #pragma unroll
        for (int j = 0; j < 8; ++j) {
            const float Sx  = VSx[j]  + VSx[j+1]  + VSx[j+2];
            const float Sy  = VSy[j]  + VSy[j+1]  + VSy[j+2];
            const float Sxx = VSxx[j] + VSxx[j+1] + VSxx[j+2];
            const float Syy = VSyy[j] + VSyy[j+1] + VSyy[j+2];
            const float Sxy = VSxy[j] + VSxy[j+1] + VSxy[j+2];

            const float mux   = Sx * inv9;
            const float muy   = Sy * inv9;
            const float mux2  = mux * mux;
            const float muy2  = muy * muy;
            const float muxy  = mux * muy;
            const float sigx  = fmaf(Sxx, inv9, -mux2);
            const float sigy  = fmaf(Syy, inv9, -muy2);
            const float sigxy = fmaf(Sxy, inv9, -muxy);

            const float nume = fmaf(2.0f, muxy, C1v) * fmaf(2.0f, sigxy, C2v);
            const float deno = (mux2 + muy2 + C1v) * (sigx + sigy + C2v);
            float v = fmaf(nume, -__builtin_amdgcn_rcpf(deno), 1.0f) * 0.5f;
            v = fminf(fmaxf(v, 0.0f), 1.0f);
            acc += v;
        }
    }

    #pragma unroll
    for (int off = 32; off > 0; off >>= 1)
        acc += __shfl_down(acc, off);

    __shared__ float wave_sums[WAVES_PER_BLOCK];
    if (lane == 0) wave_sums[wave] = acc;
    __syncthreads();
    if (threadIdx.x == 0)
        partials[blk] = wave_sums[0] + wave_sums[1] + wave_sums[2] + wave_sums[3];
}

__global__ void ssim_reduce_kernel(const float* __restrict__ partials,
                                   float* __restrict__ out) {
    float acc = 0.0f;
    for (int i = threadIdx.x; i < N_MAIN_BLOCKS; i += 256)
        acc += partials[i];
    #pragma unroll
    for (int off = 32; off > 0; off >>= 1)
        acc += __shfl_down(acc, off);
    __shared__ float wave_sums[4];
    const int wave = threadIdx.x >> 6;
    const int lane = threadIdx.x & 63;
    if (lane == 0) wave_sums[wave] = acc;
    __syncthreads();
    if (threadIdx.x == 0)
        out[0] = (wave_sums[0] + wave_sums[1] + wave_sums[2] + wave_sums[3])
                 * (1.0f / TOTAL_ELEMS);
}

extern "C" void kernel_launch(void* const* d_in, const int* in_sizes, int n_in,
                              void* d_out, int out_size, void* d_ws, size_t ws_size,
                              hipStream_t stream) {
    const float* x = (const float*)d_in[0];
    const float* y = (const float*)d_in[1];
    float* out      = (float*)d_out;
    float* partials = (float*)d_ws;   // N_MAIN_BLOCKS floats

    ssim_main_kernel<<<N_MAIN_BLOCKS, 256, 0, stream>>>(x, y, partials);
    ssim_reduce_kernel<<<1, 256, 0, stream>>>(partials, out);
}

// Round 5
// 227.018 us; speedup vs baseline: 1.1531x; 1.1531x over previous
//
#include <hip/hip_runtime.h>

// SSIM loss, fp32, x/y: (32,3,512,512), scalar mean output.
// R5: rolling 3-row register window, full-row waves, off-critical-path edges.
//   - Lane L owns cols [8L..8L+7] of a full 512-col row: 2 float4 loads per
//     input per NEW row only (rolling window => ~1.25x unique bytes requested,
//     vs 3x for the stateless R3/R4 designs).
//   - Edge cols 8L-1 / 8L+8 come from 4 shuffles per new row, applied to the
//     PREVIOUSLY prefetched row at the END of each iteration -- never to
//     just-issued loads, so the vmcnt wait for row r+2 sits after a full
//     compute body (prefetch distance = 1 body). Image-edge reflect uses the
//     lane's own registers (col -1 -> 1, col 512 -> 510) via cndmask.
//   - Raw-only state (x,y of 3 rows + 4 edge scalars each): products are
//     recomputed per iteration -- VALU is cheap, registers are not (R4's
//     spills were the lesson). __launch_bounds__(128,3) caps at ~170 VGPR.
//   - 3072 two-wave blocks (96 planes x 32 strips of 16 rows; RPW=8/wave).
//   - Block partials -> d_ws, 1-block reduce writes the mean.

#define IMG_H 512
#define IMG_W 512
#define N_PLANES 96
#define RPW 8                           // rows per wave
#define WAVES_PER_BLOCK 2
#define ROWS_PER_BLOCK (RPW * WAVES_PER_BLOCK)            // 16
#define BLOCKS_PER_PLANE (IMG_H / ROWS_PER_BLOCK)         // 32
#define N_MAIN_BLOCKS (N_PLANES * BLOCKS_PER_PLANE)       // 3072
#define TOTAL_ELEMS 25165824.0f         // 32*3*512*512

__device__ __forceinline__ int reflect512(int i) {
    i = i < 0 ? -i : i;
    return i > (IMG_H - 1) ? (2 * (IMG_H - 1) - i) : i;
}

struct Raw { float x[8], y[8]; };
struct Edge { float xl, xr, yl, yr; };

// Issue the 4 float4 loads for one (reflected) row. No cross-lane ops here.
__device__ __forceinline__ Raw load_raw(const float* __restrict__ px,
                                        const float* __restrict__ py,
                                        int r, int vidx) {
    const int rr = reflect512(r);
    const float4* bx = (const float4*)(px + (size_t)rr * IMG_W);
    const float4* by = (const float4*)(py + (size_t)rr * IMG_W);
    const float4 a = bx[vidx], b = bx[vidx + 1];
    const float4 c = by[vidx], d = by[vidx + 1];
    Raw o;
    o.x[0] = a.x; o.x[1] = a.y; o.x[2] = a.z; o.x[3] = a.w;
    o.x[4] = b.x; o.x[5] = b.y; o.x[6] = b.z; o.x[7] = b.w;
    o.y[0] = c.x; o.y[1] = c.y; o.y[2] = c.z; o.y[3] = c.w;
    o.y[4] = d.x; o.y[5] = d.y; o.y[6] = d.z; o.y[7] = d.w;
    return o;
}

// Cross-lane edge exchange for an already-landed row (4 shuffles + cndmask).
__device__ __forceinline__ Edge make_edge(const Raw& r, int lane) {
    const float xl = __shfl_up(r.x[7], 1);
    const float yl = __shfl_up(r.y[7], 1);
    const float xr = __shfl_down(r.x[0], 1);
    const float yr = __shfl_down(r.y[0], 1);
    Edge e;
    e.xl = (lane == 0)  ? r.x[1] : xl;   // col -1  -> col 1 (reflect)
    e.yl = (lane == 0)  ? r.y[1] : yl;
    e.xr = (lane == 63) ? r.x[6] : xr;   // col 512 -> col 510 (reflect)
    e.yr = (lane == 63) ? r.y[6] : yr;
    return e;
}

__global__ __launch_bounds__(128, 3)
void ssim_main_kernel(const float* __restrict__ x, const float* __restrict__ y,
                      float* __restrict__ partials) {
    const int blk   = blockIdx.x;
    const int plane = blk / BLOCKS_PER_PLANE;
    const int sblk  = blk % BLOCKS_PER_PLANE;
    const int wave  = threadIdx.x >> 6;
    const int lane  = threadIdx.x & 63;

    const int r0   = (sblk * WAVES_PER_BLOCK + wave) * RPW;
    const int vidx = lane * 2;

    const float* px = x + (size_t)plane * (IMG_H * IMG_W);
    const float* py = y + (size_t)plane * (IMG_H * IMG_W);

    const float C1v  = 0.0001f;   // 0.01^2
    const float C2v  = 0.0009f;   // 0.03^2
    const float inv9 = 1.0f / 9.0f;

    // Prologue: window rows r0-1, r0, r0+1
    Raw  w0 = load_raw(px, py, r0 - 1, vidx);
    Raw  w1 = load_raw(px, py, r0,     vidx);
    Raw  w2 = load_raw(px, py, r0 + 1, vidx);
    Edge e0 = make_edge(w0, lane);
    Edge e1 = make_edge(w1, lane);
    Edge e2 = make_edge(w2, lane);

    float acc = 0.0f;

    #pragma unroll
    for (int i = 0; i < RPW; ++i) {
        // Prefetch row r+2 (reflect keeps it valid; last iter's value IS the
        // reflected window row for output row 511, so always correct).
        Raw wn = load_raw(px, py, r0 + 2 + i, vidx);

        // ---- vertical 3-row sums, 10 columns [8L-1, 8L..8L+7, 8L+8] ----
        float VSx[10], VSy[10], VSxx[10], VSyy[10], VSxy[10];
        {   // left edge (col 8L-1)
            const float x1 = e0.xl, x2 = e1.xl, x3 = e2.xl;
            const float y1 = e0.yl, y2 = e1.yl, y3 = e2.yl;
            VSx[0]  = x1 + x2 + x3;
            VSy[0]  = y1 + y2 + y3;
            VSxx[0] = fmaf(x1, x1, fmaf(x2, x2, x3 * x3));
            VSyy[0] = fmaf(y1, y1, fmaf(y2, y2, y3 * y3));
            VSxy[0] = fmaf(x1, y1, fmaf(x2, y2, x3 * y3));
        }
        #pragma unroll
        for (int c = 0; c < 8; ++c) {
            const float x1 = w0.x[c], x2 = w1.x[c], x3 = w2.x[c];
            const float y1 = w0.y[c], y2 = w1.y[c], y3 = w2.y[c];
            VSx[c+1]  = x1 + x2 + x3;
            VSy[c+1]  = y1 + y2 + y3;
            VSxx[c+1] = fmaf(x1, x1, fmaf(x2, x2, x3 * x3));
            VSyy[c+1] = fmaf(y1, y1, fmaf(y2, y2, y3 * y3));
            VSxy[c+1] = fmaf(x1, y1, fmaf(x2, y2, x3 * y3));
        }
        {   // right edge (col 8L+8)
            const float x1 = e0.xr, x2 = e1.xr, x3 = e2.xr;
            const float y1 = e0.yr, y2 = e1.yr, y3 = e2.yr;
            VSx[9]  = x1 + x2 + x3;
            VSy[9]  = y1 + y2 + y3;
            VSxx[9] = fmaf(x1, x1, fmaf(x2, x2, x3 * x3));
            VSyy[9] = fmaf(y1, y1, fmaf(y2, y2, y3 * y3));
            VSxy[9] = fmaf(x1, y1, fmaf(x2, y2, x3 * y3));
        }

        // ---- horizontal 3-tap + SSIM ----
        #pragma unroll
        for (int j = 0; j < 8; ++j) {
            const float Sx  = VSx[j]  + VSx[j+1]  + VSx[j+2];
            const float Sy  = VSy[j]  + VSy[j+1]  + VSy[j+2];
            const float Sxx = VSxx[j] + VSxx[j+1] + VSxx[j+2];
            const float Syy = VSyy[j] + VSyy[j+1] + VSyy[j+2];
            const float Sxy = VSxy[j] + VSxy[j+1] + VSxy[j+2];

            const float mux   = Sx * inv9;
            const float muy   = Sy * inv9;
            const float mux2  = mux * mux;
            const float muy2  = muy * muy;
            const float muxy  = mux * muy;
            const float sigx  = fmaf(Sxx, inv9, -mux2);
            const float sigy  = fmaf(Syy, inv9, -muy2);
            const float sigxy = fmaf(Sxy, inv9, -muxy);

            const float nume = fmaf(2.0f, muxy, C1v) * fmaf(2.0f, sigxy, C2v);
            const float deno = (mux2 + muy2 + C1v) * (sigx + sigy + C2v);
            float v = fmaf(nume, -__builtin_amdgcn_rcpf(deno), 1.0f) * 0.5f;
            v = fminf(fmaxf(v, 0.0f), 1.0f);
            acc += v;
        }

        // Edge exchange for the prefetched row (its loads have had a full
        // compute body to land), then rotate the window.
        Edge en = make_edge(wn, lane);
        w0 = w1; w1 = w2; w2 = wn;
        e0 = e1; e1 = e2; e2 = en;
    }

    #pragma unroll
    for (int off = 32; off > 0; off >>= 1)
        acc += __shfl_down(acc, off);

    __shared__ float wave_sums[WAVES_PER_BLOCK];
    if (lane == 0) wave_sums[wave] = acc;
    __syncthreads();
    if (threadIdx.x == 0)
        partials[blk] = wave_sums[0] + wave_sums[1];
}

__global__ void ssim_reduce_kernel(const float* __restrict__ partials,
                                   float* __restrict__ out) {
    float acc = 0.0f;
    for (int i = threadIdx.x; i < N_MAIN_BLOCKS; i += 256)
        acc += partials[i];
    #pragma unroll
    for (int off = 32; off > 0; off >>= 1)
        acc += __shfl_down(acc, off);
    __shared__ float wave_sums[4];
    const int wave = threadIdx.x >> 6;
    const int lane = threadIdx.x & 63;
    if (lane == 0) wave_sums[wave] = acc;
    __syncthreads();
    if (threadIdx.x == 0)
        out[0] = (wave_sums[0] + wave_sums[1] + wave_sums[2] + wave_sums[3])
                 * (1.0f / TOTAL_ELEMS);
}

extern "C" void kernel_launch(void* const* d_in, const int* in_sizes, int n_in,
                              void* d_out, int out_size, void* d_ws, size_t ws_size,
                              hipStream_t stream) {
    const float* x = (const float*)d_in[0];
    const float* y = (const float*)d_in[1];
    float* out      = (float*)d_out;
    float* partials = (float*)d_ws;   // N_MAIN_BLOCKS floats

    ssim_main_kernel<<<N_MAIN_BLOCKS, 128, 0, stream>>>(x, y, partials);
    ssim_reduce_kernel<<<1, 256, 0, stream>>>(partials, out);
}

// Round 6
// 224.503 us; speedup vs baseline: 1.1660x; 1.0112x over previous
//
#include <hip/hip_runtime.h>

// SSIM loss, fp32, x/y: (32,3,512,512), scalar mean output.
// R6: single-wave blocks + partial unroll + pinned prefetch registers.
//   - Diagnosis from R2-R5: compiler caps VGPR at ~64 and spills/remats any
//     larger rolling-window state to scratch (R4: +67MB writes, R5: +40MB).
//     Fixes: __launch_bounds__(64,1) (VGPR budget 512, single-wave blocks,
//     no barriers), unroll 2 instead of full (backedge keeps window live),
//     asm-pin the prefetched row (non-rematerializable, and the vmcnt wait
//     lands at the END of the compute body -> prefetch distance = 1 body).
//   - Lane L owns cols [8L..8L+7] of a full 512-col row (2 float4 per input
//     per new row). Rolling 3-row raw window; edges via 4 shuffles per new
//     row applied to the previously-prefetched row. Image-edge reflect is
//     lane-local register selection. 1.125x read redundancy (RPW=16).
//   - Grid: 96 planes x 32 strips = 3072 single-wave blocks = 12 waves/CU.
//   - Wave partials -> d_ws, 1-block reduce writes the mean.

#define IMG_H 512
#define IMG_W 512
#define N_PLANES 96
#define RPW 16                          // rows per wave/block
#define BLOCKS_PER_PLANE (IMG_H / RPW)                    // 32
#define N_MAIN_BLOCKS (N_PLANES * BLOCKS_PER_PLANE)       // 3072
#define TOTAL_ELEMS 25165824.0f         // 32*3*512*512

__device__ __forceinline__ int reflect512(int i) {
    i = i < 0 ? -i : i;
    return i > (IMG_H - 1) ? (2 * (IMG_H - 1) - i) : i;
}

struct Raw { float x[8], y[8]; };
struct Edge { float xl, xr, yl, yr; };

// Issue the 4 float4 loads for one (reflected) row. No cross-lane ops here.
__device__ __forceinline__ Raw load_raw(const float* __restrict__ px,
                                        const float* __restrict__ py,
                                        int r, int vidx) {
    const int rr = reflect512(r);
    const float4* bx = (const float4*)(px + (size_t)rr * IMG_W);
    const float4* by = (const float4*)(py + (size_t)rr * IMG_W);
    const float4 a = bx[vidx], b = bx[vidx + 1];
    const float4 c = by[vidx], d = by[vidx + 1];
    Raw o;
    o.x[0] = a.x; o.x[1] = a.y; o.x[2] = a.z; o.x[3] = a.w;
    o.x[4] = b.x; o.x[5] = b.y; o.x[6] = b.z; o.x[7] = b.w;
    o.y[0] = c.x; o.y[1] = c.y; o.y[2] = c.z; o.y[3] = c.w;
    o.y[4] = d.x; o.y[5] = d.y; o.y[6] = d.z; o.y[7] = d.w;
    return o;
}

// Force the row to live in VGPRs: opaque to remat/sinking; also places the
// vmcnt wait for these loads exactly here.
__device__ __forceinline__ void pin(Raw& r) {
    asm volatile("" :
        "+v"(r.x[0]), "+v"(r.x[1]), "+v"(r.x[2]), "+v"(r.x[3]),
        "+v"(r.x[4]), "+v"(r.x[5]), "+v"(r.x[6]), "+v"(r.x[7]),
        "+v"(r.y[0]), "+v"(r.y[1]), "+v"(r.y[2]), "+v"(r.y[3]),
        "+v"(r.y[4]), "+v"(r.y[5]), "+v"(r.y[6]), "+v"(r.y[7]));
}

// Cross-lane edge exchange for an already-landed row (4 shuffles + cndmask).
__device__ __forceinline__ Edge make_edge(const Raw& r, int lane) {
    const float xl = __shfl_up(r.x[7], 1);
    const float yl = __shfl_up(r.y[7], 1);
    const float xr = __shfl_down(r.x[0], 1);
    const float yr = __shfl_down(r.y[0], 1);
    Edge e;
    e.xl = (lane == 0)  ? r.x[1] : xl;   // col -1  -> col 1 (reflect)
    e.yl = (lane == 0)  ? r.y[1] : yl;
    e.xr = (lane == 63) ? r.x[6] : xr;   // col 512 -> col 510 (reflect)
    e.yr = (lane == 63) ? r.y[6] : yr;
    return e;
}

__global__ __launch_bounds__(64, 1)
void ssim_main_kernel(const float* __restrict__ x, const float* __restrict__ y,
                      float* __restrict__ partials) {
    const int blk   = blockIdx.x;
    const int plane = blk / BLOCKS_PER_PLANE;
    const int sblk  = blk % BLOCKS_PER_PLANE;
    const int lane  = threadIdx.x;        // single wave per block

    const int r0   = sblk * RPW;
    const int vidx = lane * 2;

    const float* px = x + (size_t)plane * (IMG_H * IMG_W);
    const float* py = y + (size_t)plane * (IMG_H * IMG_W);

    const float C1v  = 0.0001f;   // 0.01^2
    const float C2v  = 0.0009f;   // 0.03^2
    const float inv9 = 1.0f / 9.0f;

    // Prologue: window rows r0-1, r0, r0+1
    Raw  w0 = load_raw(px, py, r0 - 1, vidx);
    Raw  w1 = load_raw(px, py, r0,     vidx);
    Raw  w2 = load_raw(px, py, r0 + 1, vidx);
    Edge e0 = make_edge(w0, lane);
    Edge e1 = make_edge(w1, lane);
    Edge e2 = make_edge(w2, lane);

    float acc = 0.0f;

    #pragma unroll 2
    for (int i = 0; i < RPW; ++i) {
        // Prefetch row r+2 (becomes w2 next iteration; reflect keeps it
        // correct for the bottom edge).
        Raw wn = load_raw(px, py, r0 + 2 + i, vidx);

        // ---- vertical 3-row sums, 10 columns [8L-1, 8L..8L+7, 8L+8] ----
        float VSx[10], VSy[10], VSxx[10], VSyy[10], VSxy[10];
        {   // left edge (col 8L-1)
            const float x1 = e0.xl, x2 = e1.xl, x3 = e2.xl;
            const float y1 = e0.yl, y2 = e1.yl, y3 = e2.yl;
            VSx[0]  = x1 + x2 + x3;
            VSy[0]  = y1 + y2 + y3;
            VSxx[0] = fmaf(x1, x1, fmaf(x2, x2, x3 * x3));
            VSyy[0] = fmaf(y1, y1, fmaf(y2, y2, y3 * y3));
            VSxy[0] = fmaf(x1, y1, fmaf(x2, y2, x3 * y3));
        }
        #pragma unroll
        for (int c = 0; c < 8; ++c) {
            const float x1 = w0.x[c], x2 = w1.x[c], x3 = w2.x[c];
            const float y1 = w0.y[c], y2 = w1.y[c], y3 = w2.y[c];
            VSx[c+1]  = x1 + x2 + x3;
            VSy[c+1]  = y1 + y2 + y3;
            VSxx[c+1] = fmaf(x1, x1, fmaf(x2, x2, x3 * x3));
            VSyy[c+1] = fmaf(y1, y1, fmaf(y2, y2, y3 * y3));
            VSxy[c+1] = fmaf(x1, y1, fmaf(x2, y2, x3 * y3));
        }
        {   // right edge (col 8L+8)
            const float x1 = e0.xr, x2 = e1.xr, x3 = e2.xr;
            const float y1 = e0.yr, y2 = e1.yr, y3 = e2.yr;
            VSx[9]  = x1 + x2 + x3;
            VSy[9]  = y1 + y2 + y3;
            VSxx[9] = fmaf(x1, x1, fmaf(x2, x2, x3 * x3));
            VSyy[9] = fmaf(y1, y1, fmaf(y2, y2, y3 * y3));
            VSxy[9] = fmaf(x1, y1, fmaf(x2, y2, x3 * y3));
        }

        // ---- horizontal 3-tap + SSIM ----
        #pragma unroll
        for (int j = 0; j < 8; ++j) {
            const float Sx  = VSx[j]  + VSx[j+1]  + VSx[j+2];
            const float Sy  = VSy[j]  + VSy[j+1]  + VSy[j+2];
            const float Sxx = VSxx[j] + VSxx[j+1] + VSxx[j+2];
            const float Syy = VSyy[j] + VSyy[j+1] + VSyy[j+2];
            const float Sxy = VSxy[j] + VSxy[j+1] + VSxy[j+2];

            const float mux   = Sx * inv9;
            const float muy   = Sy * inv9;
            const float mux2  = mux * mux;
            const float muy2  = muy * muy;
            const float muxy  = mux * muy;
            const float sigx  = fmaf(Sxx, inv9, -mux2);
            const float sigy  = fmaf(Syy, inv9, -muy2);
            const float sigxy = fmaf(Sxy, inv9, -muxy);

            const float nume = fmaf(2.0f, muxy, C1v) * fmaf(2.0f, sigxy, C2v);
            const float deno = (mux2 + muy2 + C1v) * (sigx + sigy + C2v);
            float v = fmaf(nume, -__builtin_amdgcn_rcpf(deno), 1.0f) * 0.5f;
            v = fminf(fmaxf(v, 0.0f), 1.0f);
            acc += v;
        }

        // The prefetched row's loads have had a full body to land; pin it
        // into registers (wait lands here), exchange edges, rotate.
        pin(wn);
        Edge en = make_edge(wn, lane);
        w0 = w1; w1 = w2; w2 = wn;
        e0 = e1; e1 = e2; e2 = en;
    }

    // Single-wave block: shuffle reduction only, lane 0 writes the partial.
    #pragma unroll
    for (int off = 32; off > 0; off >>= 1)
        acc += __shfl_down(acc, off);
    if (lane == 0) partials[blk] = acc;
}

__global__ void ssim_reduce_kernel(const float* __restrict__ partials,
                                   float* __restrict__ out) {
    float acc = 0.0f;
    for (int i = threadIdx.x; i < N_MAIN_BLOCKS; i += 256)
        acc += partials[i];
    #pragma unroll
    for (int off = 32; off > 0; off >>= 1)
        acc += __shfl_down(acc, off);
    __shared__ float wave_sums[4];
    const int wave = threadIdx.x >> 6;
    const int lane = threadIdx.x & 63;
    if (lane == 0) wave_sums[wave] = acc;
    __syncthreads();
    if (threadIdx.x == 0)
        out[0] = (wave_sums[0] + wave_sums[1] + wave_sums[2] + wave_sums[3])
                 * (1.0f / TOTAL_ELEMS);
}

extern "C" void kernel_launch(void* const* d_in, const int* in_sizes, int n_in,
                              void* d_out, int out_size, void* d_ws, size_t ws_size,
                              hipStream_t stream) {
    const float* x = (const float*)d_in[0];
    const float* y = (const float*)d_in[1];
    float* out      = (float*)d_out;
    float* partials = (float*)d_ws;   // N_MAIN_BLOCKS floats

    ssim_main_kernel<<<N_MAIN_BLOCKS, 64, 0, stream>>>(x, y, partials);
    ssim_reduce_kernel<<<1, 256, 0, stream>>>(partials, out);
}

// Round 7
// 218.201 us; speedup vs baseline: 1.1997x; 1.0289x over previous
//
#include <hip/hip_runtime.h>

// SSIM loss, fp32, x/y: (32,3,512,512), scalar mean output.
// R7: 4 cols/lane rolling window -- state small enough to never spill.
//   - R4/R5/R6 lesson: the 8-cols/lane rolling window (~140 live floats)
//     always spills (+40..67MB scratch writes, reloads at global latency in
//     the dependency chain). Halving to 4 cols/lane cuts carried state to
//     3 rows x 8 floats + 12 edge floats ~= 40, peak ~100 VGPR incl.
//     transients -> fits the 128-VGPR cap of __launch_bounds__(256,4) with
//     margin -> 4 waves/SIMD (16 waves/CU) AND no scratch.
//   - Wave covers a 256-col tile; lane L owns cols t0+4L..4L+3 (one float4
//     per input per new row). Interior tile boundary: ONE masked scalar halo
//     load per side per row (lane 0 of tile 1 needs col 255; lane 63 of
//     tile 0 needs col 256). Image edges reflect to the lane's own regs.
//   - Rolling 3-row window, prefetch distance = 1 body; edge shuffles (4/row)
//     run at body END on the already-landed prefetched row.
//   - Grid: 96 planes x 2 tiles x 8 strips = 1536 blocks of 4 waves
//     (6 blocks/CU), RPW=16 -> read redundancy 1.125x.
//   - Block partials -> d_ws, 1-block reduce writes the mean.

#define IMG_H 512
#define IMG_W 512
#define N_PLANES 96
#define TILE_W 256
#define N_TILES 2
#define RPW 16                          // rows per wave
#define WAVES_PER_BLOCK 4
#define ROWS_PER_BLOCK (RPW * WAVES_PER_BLOCK)            // 64
#define STRIPS (IMG_H / ROWS_PER_BLOCK)                   // 8
#define N_MAIN_BLOCKS (N_PLANES * N_TILES * STRIPS)       // 1536
#define TOTAL_ELEMS 25165824.0f         // 32*3*512*512

__device__ __forceinline__ int reflect512(int i) {
    i = i < 0 ? -i : i;
    return i > (IMG_H - 1) ? (2 * (IMG_H - 1) - i) : i;
}

struct Raw4 {
    float x[4], y[4];   // this lane's 4 columns
    float hx, hy;       // halo col (only meaningful on the designated lane)
};
struct Edge { float xl, xr, yl, yr; };

// One (reflected) row: 1 float4 per input + masked scalar halo.
__device__ __forceinline__ Raw4 load_raw(const float* __restrict__ px,
                                         const float* __restrict__ py,
                                         int r, int c4idx,
                                         bool haloNeed, int haloCol) {
    const int rr = reflect512(r);
    const size_t rowb = (size_t)rr * IMG_W;
    const float4 a = ((const float4*)(px + rowb))[c4idx];
    const float4 b = ((const float4*)(py + rowb))[c4idx];
    Raw4 o;
    o.x[0] = a.x; o.x[1] = a.y; o.x[2] = a.z; o.x[3] = a.w;
    o.y[0] = b.x; o.y[1] = b.y; o.y[2] = b.z; o.y[3] = b.w;
    o.hx = 0.0f; o.hy = 0.0f;
    if (haloNeed) {
        o.hx = px[rowb + haloCol];
        o.hy = py[rowb + haloCol];
    }
    return o;
}

// Edge exchange for an already-landed row: 4 shuffles + lane-local selects.
// tile 0, lane 0 : col -1 -> reflect col 1  = own x[1]
// tile 1, lane 0 : col 255 = halo load
// tile 0, lane 63: col 256 = halo load
// tile 1, lane 63: col 512 -> reflect col 510 = own x[2]
__device__ __forceinline__ Edge make_edge(const Raw4& r, int lane, int tile) {
    const float xl = __shfl_up(r.x[3], 1);
    const float yl = __shfl_up(r.y[3], 1);
    const float xr = __shfl_down(r.x[0], 1);
    const float yr = __shfl_down(r.y[0], 1);
    Edge e;
    e.xl = xl; e.yl = yl; e.xr = xr; e.yr = yr;
    if (lane == 0) {
        e.xl = (tile == 0) ? r.x[1] : r.hx;
        e.yl = (tile == 0) ? r.y[1] : r.hy;
    }
    if (lane == 63) {
        e.xr = (tile == 1) ? r.x[2] : r.hx;
        e.yr = (tile == 1) ? r.y[2] : r.hy;
    }
    return e;
}

__global__ __launch_bounds__(256, 4)
void ssim_main_kernel(const float* __restrict__ x, const float* __restrict__ y,
                      float* __restrict__ partials) {
    const int blk   = blockIdx.x;
    const int plane = blk / (N_TILES * STRIPS);
    const int rem   = blk % (N_TILES * STRIPS);
    const int tile  = rem / STRIPS;
    const int strip = rem % STRIPS;
    const int wave  = threadIdx.x >> 6;
    const int lane  = threadIdx.x & 63;

    const int r0    = (strip * WAVES_PER_BLOCK + wave) * RPW;
    const int c4idx = tile * (TILE_W / 4) + lane;

    // Halo: lane 0 of tile 1 needs col 255; lane 63 of tile 0 needs col 256.
    const bool haloNeed = (lane == 0 && tile == 1) || (lane == 63 && tile == 0);
    const int  haloCol  = (lane == 0) ? (TILE_W - 1) : TILE_W;  // 255 or 256

    const float* px = x + (size_t)plane * (IMG_H * IMG_W);
    const float* py = y + (size_t)plane * (IMG_H * IMG_W);

    const float C1v  = 0.0001f;   // 0.01^2
    const float C2v  = 0.0009f;   // 0.03^2
    const float inv9 = 1.0f / 9.0f;

    // Prologue: window rows r0-1, r0, r0+1
    Raw4 w0 = load_raw(px, py, r0 - 1, c4idx, haloNeed, haloCol);
    Raw4 w1 = load_raw(px, py, r0,     c4idx, haloNeed, haloCol);
    Raw4 w2 = load_raw(px, py, r0 + 1, c4idx, haloNeed, haloCol);
    Edge e0 = make_edge(w0, lane, tile);
    Edge e1 = make_edge(w1, lane, tile);
    Edge e2 = make_edge(w2, lane, tile);

    float acc = 0.0f;

    for (int i = 0; i < RPW; ++i) {
        // Prefetch row r+2 (used NEXT iteration; its wait lands at body end).
        Raw4 wn = load_raw(px, py, r0 + 2 + i, c4idx, haloNeed, haloCol);

        // ---- vertical 3-row sums, 6 columns [c-1, c0..c3, c+4] ----
        float VSx[6], VSy[6], VSxx[6], VSyy[6], VSxy[6];
        {   // left edge
            const float x1 = e0.xl, x2 = e1.xl, x3 = e2.xl;
            const float y1 = e0.yl, y2 = e1.yl, y3 = e2.yl;
            VSx[0]  = x1 + x2 + x3;
            VSy[0]  = y1 + y2 + y3;
            VSxx[0] = fmaf(x1, x1, fmaf(x2, x2, x3 * x3));
            VSyy[0] = fmaf(y1, y1, fmaf(y2, y2, y3 * y3));
            VSxy[0] = fmaf(x1, y1, fmaf(x2, y2, x3 * y3));
        }
        #pragma unroll
        for (int c = 0; c < 4; ++c) {
            const float x1 = w0.x[c], x2 = w1.x[c], x3 = w2.x[c];
            const float y1 = w0.y[c], y2 = w1.y[c], y3 = w2.y[c];
            VSx[c+1]  = x1 + x2 + x3;
            VSy[c+1]  = y1 + y2 + y3;
            VSxx[c+1] = fmaf(x1, x1, fmaf(x2, x2, x3 * x3));
            VSyy[c+1] = fmaf(y1, y1, fmaf(y2, y2, y3 * y3));
            VSxy[c+1] = fmaf(x1, y1, fmaf(x2, y2, x3 * y3));
        }
        {   // right edge
            const float x1 = e0.xr, x2 = e1.xr, x3 = e2.xr;
            const float y1 = e0.yr, y2 = e1.yr, y3 = e2.yr;
            VSx[5]  = x1 + x2 + x3;
            VSy[5]  = y1 + y2 + y3;
            VSxx[5] = fmaf(x1, x1, fmaf(x2, x2, x3 * x3));
            VSyy[5] = fmaf(y1, y1, fmaf(y2, y2, y3 * y3));
            VSxy[5] = fmaf(x1, y1, fmaf(x2, y2, x3 * y3));
        }

        // ---- horizontal 3-tap + SSIM, 4 output columns ----
        #pragma unroll
        for (int j = 0; j < 4; ++j) {
            const float Sx  = VSx[j]  + VSx[j+1]  + VSx[j+2];
            const float Sy  = VSy[j]  + VSy[j+1]  + VSy[j+2];
            const float Sxx = VSxx[j] + VSxx[j+1] + VSxx[j+2];
            const float Syy = VSyy[j] + VSyy[j+1] + VSyy[j+2];
            const float Sxy = VSxy[j] + VSxy[j+1] + VSxy[j+2];

            const float mux   = Sx * inv9;
            const float muy   = Sy * inv9;
            const float mux2  = mux * mux;
            const float muy2  = muy * muy;
            const float muxy  = mux * muy;
            const float sigx  = fmaf(Sxx, inv9, -mux2);
            const float sigy  = fmaf(Syy, inv9, -muy2);
            const float sigxy = fmaf(Sxy, inv9, -muxy);

            const float nume = fmaf(2.0f, muxy, C1v) * fmaf(2.0f, sigxy, C2v);
            const float deno = (mux2 + muy2 + C1v) * (sigx + sigy + C2v);
            float v = fmaf(nume, -__builtin_amdgcn_rcpf(deno), 1.0f) * 0.5f;
            v = fminf(fmaxf(v, 0.0f), 1.0f);
            acc += v;
        }

        // Prefetched row has had a full body to land: exchange edges, rotate.
        Edge en = make_edge(wn, lane, tile);
        w0 = w1; w1 = w2; w2 = wn;
        e0 = e1; e1 = e2; e2 = en;
    }

    #pragma unroll
    for (int off = 32; off > 0; off >>= 1)
        acc += __shfl_down(acc, off);

    __shared__ float wave_sums[WAVES_PER_BLOCK];
    if (lane == 0) wave_sums[wave] = acc;
    __syncthreads();
    if (threadIdx.x == 0)
        partials[blk] = wave_sums[0] + wave_sums[1] + wave_sums[2] + wave_sums[3];
}

__global__ void ssim_reduce_kernel(const float* __restrict__ partials,
                                   float* __restrict__ out) {
    float acc = 0.0f;
    for (int i = threadIdx.x; i < N_MAIN_BLOCKS; i += 256)
        acc += partials[i];
    #pragma unroll
    for (int off = 32; off > 0; off >>= 1)
        acc += __shfl_down(acc, off);
    __shared__ float wave_sums[4];
    const int wave = threadIdx.x >> 6;
    const int lane = threadIdx.x & 63;
    if (lane == 0) wave_sums[wave] = acc;
    __syncthreads();
    if (threadIdx.x == 0)
        out[0] = (wave_sums[0] + wave_sums[1] + wave_sums[2] + wave_sums[3])
                 * (1.0f / TOTAL_ELEMS);
}

extern "C" void kernel_launch(void* const* d_in, const int* in_sizes, int n_in,
                              void* d_out, int out_size, void* d_ws, size_t ws_size,
                              hipStream_t stream) {
    const float* x = (const float*)d_in[0];
    const float* y = (const float*)d_in[1];
    float* out      = (float*)d_out;
    float* partials = (float*)d_ws;   // N_MAIN_BLOCKS floats

    ssim_main_kernel<<<N_MAIN_BLOCKS, 256, 0, stream>>>(x, y, partials);
    ssim_reduce_kernel<<<1, 256, 0, stream>>>(partials, out);
}